// Round 24
// baseline (115.936 us; speedup 1.0000x reference)
//
#include <hip/hip_runtime.h>

typedef __bf16 bf16x8 __attribute__((ext_vector_type(8)));
typedef float f32x4 __attribute__((ext_vector_type(4)));

#define XS_COLS 66
#define XS_CHP_B 48                            // 16ch*2B + 16B pad; 16-aligned
#define XS_SLOT_B (XS_COLS * XS_CHP_B)         // 3168 B per row-slot
#define H_BYTES 16384                          // H[64 px][128 k] bf16, XOR-swizzled
#define OFF_XS H_BYTES
#define SMEM_BYTES (H_BYTES + 4 * XS_SLOT_B)   // 29056 B

__device__ __forceinline__ unsigned short bfbits(float f) {
    __bf16 b = (__bf16)f;
    return __builtin_bit_cast(unsigned short, b);
}
__device__ __forceinline__ float bf2f(unsigned short u) {
    return __uint_as_float((unsigned int)u << 16);
}

__global__ __launch_bounds__(256, 4) void nca_main(
    const float* __restrict__ x, const float* __restrict__ rm,
    const float* __restrict__ W1, const float* __restrict__ b1,
    const float* __restrict__ W2, const float* __restrict__ b2,
    float* __restrict__ out, unsigned int* __restrict__ am)
{
    __shared__ __align__(16) char smem[SMEM_BYTES];
    char* Hb  = smem;
    char* XSb = smem + OFF_XS;

    const int tid  = threadIdx.x;
    const int lane = tid & 63;
    const int wid  = tid >> 6;      // 0..3
    const int lrow = lane & 15;
    const int kg   = lane >> 4;     // 0..3
    const int kgh  = kg >> 1;       // 0..1
    const int kgl  = kg & 1;

    // block -> (img, row-group of 32, col-strip of 64); 1024 blocks, XCD-chunked
    int raw = blockIdx.x;
    int wg  = (raw & 7) * 128 + (raw >> 3);
    int img = wg >> 5;
    int rem = wg & 31;
    int h0  = (rem >> 2) * 32;
    int w0  = (rem & 3) << 6;

    const size_t imgbase = (size_t)img * 65536;
    const int r = wid;              // n-pair: this wave owns n-tiles 2r, 2r+1

    // ---- Wt fragments (conv folded into W1; 6 nonzero taps, K=96) ----
    // taps tp: 0:(-1,-1) 1:(-1,0) 2:(-1,+1) 3:(0,-1) 4:(0,+1) 5:(+1,0)
    bf16x8 wt[2][3];
    #pragma unroll
    for (int m = 0; m < 2; ++m) {
        int n = (r * 2 + m) * 16 + lrow;
        #pragma unroll
        for (int kk = 0; kk < 3; ++kk) {
            float c0, c1, c2;
            if (kk == 0) {        // tp0 / tp1
                c0 = kgh ? -0.25f : -0.125f; c1 = 0.f; c2 = kgh ? 0.25f : 0.125f;
            } else if (kk == 1) { // tp2 / tp3
                c0 = -0.125f;
                c1 = kgh ? -0.25f  : 0.f;
                c2 = kgh ? -0.125f : 0.125f;
            } else {              // tp4 / tp5
                c0 = kgh ? 0.f : 0.125f; c1 = kgh ? 1.f : 0.25f; c2 = kgh ? 0.f : 0.125f;
            }
            bf16x8 v;
            #pragma unroll
            for (int j = 0; j < 8; ++j) {
                int ch = kgl * 8 + j;
                float wv = c0 * W1[(3 * ch + 0) * 128 + n]
                         + c1 * W1[(3 * ch + 1) * 128 + n]
                         + c2 * W1[(3 * ch + 2) * 128 + n];
                v[j] = (__bf16)wv;
            }
            wt[m][kk] = v;
        }
    }

    // W2 fragments (A-operand of transposed GEMM2: rows = out-channel c = lrow)
    bf16x8 w2f[4];
    #pragma unroll
    for (int kk = 0; kk < 4; ++kk) {
        bf16x8 v;
        #pragma unroll
        for (int j = 0; j < 8; ++j)
            v[j] = (__bf16)W2[(kk * 32 + kg * 8 + j) * 16 + lrow];
        w2f[kk] = v;
    }

    f32x4 b1q[2];
    #pragma unroll
    for (int m = 0; m < 2; ++m)
        b1q[m] = *reinterpret_cast<const f32x4*>(b1 + (r * 2 + m) * 16 + kg * 4);
    const f32x4 b2q = *reinterpret_cast<const f32x4*>(b2 + kg * 4);

    // ---- prologue: stage rows h0-1 .. h0+1 into XS ring (slot = row mod 4) ----
    for (int idx = tid; idx < 3 * 264; idx += 256) {
        int rr  = idx / 264;
        int q   = idx - rr * 264;
        int col = q >> 2, chq = q & 3;
        int gh = h0 - 1 + rr, gw = w0 + col - 1;
        int slot = (gh + 4) & 3;
        float4 v = make_float4(0.f, 0.f, 0.f, 0.f);
        if (gh >= 0 && gh < 256 && gw >= 0 && gw < 256)
            v = *reinterpret_cast<const float4*>(x + (imgbase + (size_t)gh * 256 + gw) * 16 + chq * 4);
        ushort4 qq = { bfbits(v.x), bfbits(v.y), bfbits(v.z), bfbits(v.w) };
        *reinterpret_cast<ushort4*>(XSb + slot * XS_SLOT_B + col * XS_CHP_B + chq * 8) = qq;
    }
    __syncthreads();

    const int pxl2 = wid * 16 + lrow;   // pixel this lane owns in P2 (0..63)

    for (int i = 0; i < 32; ++i) {
        int h = h0 + i;
        int sbm = ((h + 3) & 3) * XS_SLOT_B;   // row h-1
        int sb0 = ((h + 4) & 3) * XS_SLOT_B;   // row h
        int sbp = ((h + 5) & 3) * XS_SLOT_B;   // row h+1

        // ---- issue ALL P2 inputs here: covered by G1's 24 MFMA ----
        const bool do_stage = (i < 31);
        const int gh2 = h + 2;
        float4 sv0 = make_float4(0.f, 0.f, 0.f, 0.f), sv1 = make_float4(0.f, 0.f, 0.f, 0.f);
        if (do_stage) {
            int col0 = tid >> 2, chq0 = tid & 3;
            int gw = w0 + col0 - 1;
            if (gh2 < 256 && gw >= 0 && gw < 256)
                sv0 = *reinterpret_cast<const float4*>(x + (imgbase + (size_t)gh2 * 256 + gw) * 16 + chq0 * 4);
            if (tid < 8) {
                int col1 = 64 + (tid >> 2), gw1 = w0 + col1 - 1;
                if (gh2 < 256 && gw1 >= 0 && gw1 < 256)
                    sv1 = *reinterpret_cast<const float4*>(x + (imgbase + (size_t)gh2 * 256 + gw1) * 16 + (tid & 3) * 4);
            }
        }
        const unsigned int pixi = (unsigned int)(img * 65536 + h * 256 + w0 + pxl2);
        const float rmv = rm[pixi];
        const ushort4 xb = *reinterpret_cast<const ushort4*>(XSb + sb0 + (pxl2 + 1) * XS_CHP_B + kg * 8);

        // ---- P1: GEMM1 (transposed): C1T[n][px]; bias enters via MFMA C-in ----
        __builtin_amdgcn_s_setprio(1);
        #pragma unroll
        for (int t = 0; t < 4; ++t) {
            int pxl = t * 16 + lrow;                    // 0..63
            int colbase = (pxl + 1) * XS_CHP_B + kgl * 16;
            const char* a0p = XSb + sbm + colbase + (kgh ? 0 : -XS_CHP_B);
            const char* a1p = kgh ? (XSb + sb0 + colbase - XS_CHP_B) : (XSb + sbm + colbase + XS_CHP_B);
            const char* a2p = kgh ? (XSb + sbp + colbase)            : (XSb + sb0 + colbase + XS_CHP_B);
            bf16x8 bf0 = *reinterpret_cast<const bf16x8*>(a0p);
            bf16x8 bf1 = *reinterpret_cast<const bf16x8*>(a1p);
            bf16x8 bf2 = *reinterpret_cast<const bf16x8*>(a2p);
            f32x4 a0 = __builtin_amdgcn_mfma_f32_16x16x32_bf16(wt[0][0], bf0, b1q[0], 0, 0, 0);
            f32x4 a1 = __builtin_amdgcn_mfma_f32_16x16x32_bf16(wt[1][0], bf0, b1q[1], 0, 0, 0);
            a0 = __builtin_amdgcn_mfma_f32_16x16x32_bf16(wt[0][1], bf1, a0, 0, 0, 0);
            a1 = __builtin_amdgcn_mfma_f32_16x16x32_bf16(wt[1][1], bf1, a1, 0, 0, 0);
            a0 = __builtin_amdgcn_mfma_f32_16x16x32_bf16(wt[0][2], bf2, a0, 0, 0, 0);
            a1 = __builtin_amdgcn_mfma_f32_16x16x32_bf16(wt[1][2], bf2, a1, 0, 0, 0);
            #pragma unroll
            for (int m = 0; m < 2; ++m) {
                f32x4 hv = m ? a1 : a0;
                ushort4 q;
                q.x = bfbits(fmaxf(hv[0], 0.f));
                q.y = bfbits(fmaxf(hv[1], 0.f));
                q.z = bfbits(fmaxf(hv[2], 0.f));
                q.w = bfbits(fmaxf(hv[3], 0.f));
                int n0 = (r * 2 + m) * 16 + kg * 4;
                int chunk = (n0 >> 3) ^ (pxl & 7);
                *reinterpret_cast<ushort4*>(Hb + pxl * 256 + chunk * 16 + ((n0 >> 2) & 1) * 8) = q;
            }
        }
        __builtin_amdgcn_s_setprio(0);
        __syncthreads();

        // ---- P2: GEMM2T (inputs already resident); am-pack epilogue; stage writes ----
        f32x4 acc2 = {0.f, 0.f, 0.f, 0.f};
        __builtin_amdgcn_s_setprio(1);
        #pragma unroll
        for (int kk = 0; kk < 4; ++kk) {
            int chunk = (4 * kk + kg) ^ (pxl2 & 7);
            bf16x8 hb = *reinterpret_cast<const bf16x8*>(Hb + pxl2 * 256 + chunk * 16);
            acc2 = __builtin_amdgcn_mfma_f32_16x16x32_bf16(w2f[kk], hb, acc2, 0, 0, 0);
        }
        __builtin_amdgcn_s_setprio(0);
        {
            size_t pix = (size_t)pixi;
            float upd = (rmv < 0.5f) ? 1.f : 0.f;
            float4 xn;
            xn.x = bf2f(xb.x) + (acc2[0] + b2q[0]) * upd;
            xn.y = bf2f(xb.y) + (acc2[1] + b2q[1]) * upd;
            xn.z = bf2f(xb.z) + (acc2[2] + b2q[2]) * upd;
            xn.w = bf2f(xb.w) + (acc2[3] + b2q[3]) * upd;
            *reinterpret_cast<float4*>(out + pix * 16 + kg * 4) = xn;
            if (kg == 0) {
                // lo16 = alpha_new, hi16 = alpha_old (xb.w = old ch3 bits for kg==0)
                unsigned int av = ((unsigned int)xb.w << 16) | (unsigned int)bfbits(xn.w);
                am[pix] = av;
            }
        }

        if (do_stage) {
            int slot = (gh2 + 4) & 3;
            {
                int col0 = tid >> 2, chq0 = tid & 3;
                ushort4 q = { bfbits(sv0.x), bfbits(sv0.y), bfbits(sv0.z), bfbits(sv0.w) };
                *reinterpret_cast<ushort4*>(XSb + slot * XS_SLOT_B + col0 * XS_CHP_B + chq0 * 8) = q;
            }
            if (tid < 8) {
                int col1 = 64 + (tid >> 2);
                ushort4 q = { bfbits(sv1.x), bfbits(sv1.y), bfbits(sv1.z), bfbits(sv1.w) };
                *reinterpret_cast<ushort4*>(XSb + slot * XS_SLOT_B + col1 * XS_CHP_B + (tid & 3) * 8) = q;
            }
        }
        __syncthreads();
    }
}

// pass 2: 8 px per thread; both 3x3 masks from packed {alpha_new(lo), alpha_old(hi)}
__global__ __launch_bounds__(256) void nca_life(
    const unsigned int* __restrict__ am, float* __restrict__ out)
{
    int g  = blockIdx.x * 256 + threadIdx.x;   // 262144 groups of 8 px
    int q0 = g << 3;
    int w8 = q0 & 255;                         // 0,8,...,248 (aligned in row)
    int hh = (q0 >> 8) & 255;
    int imgb = q0 & ~0xFFFF;                   // image base index

    // load 3 rows x 10 cols (w8-1 .. w8+8), edge-predicated
    unsigned int v[3][10];
    #pragma unroll
    for (int dh = 0; dh < 3; ++dh) {
        int h2 = hh - 1 + dh;
        bool hv = (h2 >= 0) && (h2 <= 255);
        int base = imgb + h2 * 256;
        #pragma unroll
        for (int dw = 0; dw < 10; ++dw) {
            int w2 = w8 - 1 + dw;
            v[dh][dw] = (hv && w2 >= 0 && w2 <= 255) ? am[base + w2] : 0u;
        }
    }

    #pragma unroll
    for (int p = 0; p < 8; ++p) {
        float mn = -1e30f, mo = -1e30f;
        #pragma unroll
        for (int dh = 0; dh < 3; ++dh)
            #pragma unroll
            for (int dw = 0; dw < 3; ++dw) {
                unsigned int u = v[dh][p + dw];
                mn = fmaxf(mn, __uint_as_float(u << 16));           // alpha_new
                mo = fmaxf(mo, __uint_as_float(u & 0xffff0000u));   // alpha_old
            }
        if (!(mo > 0.1f && mn > 0.1f)) {
            float4 z = make_float4(0.f, 0.f, 0.f, 0.f);
            float4* o = (float4*)(out + (size_t)(q0 + p) * 16);
            o[0] = z; o[1] = z; o[2] = z; o[3] = z;
        }
    }
}

extern "C" void kernel_launch(void* const* d_in, const int* in_sizes, int n_in,
                              void* d_out, int out_size, void* d_ws, size_t ws_size,
                              hipStream_t stream) {
    (void)in_sizes; (void)n_in; (void)out_size; (void)ws_size;
    const float* x  = (const float*)d_in[0];
    const float* rm = (const float*)d_in[1];
    const float* W1 = (const float*)d_in[2];
    const float* b1 = (const float*)d_in[3];
    const float* W2 = (const float*)d_in[4];
    const float* b2 = (const float*)d_in[5];
    float* out = (float*)d_out;
    unsigned int* am = (unsigned int*)d_ws;   // 2M x u32 = 8 MB

    nca_main<<<dim3(1024), dim3(256), 0, stream>>>(x, rm, W1, b1, W2, b2, out, am);
    nca_life<<<dim3(1024), dim3(256), 0, stream>>>(am, out);
}

// Round 25
// 111.848 us; speedup vs baseline: 1.0366x; 1.0366x over previous
//
#include <hip/hip_runtime.h>

typedef __bf16 bf16x8 __attribute__((ext_vector_type(8)));
typedef float f32x4 __attribute__((ext_vector_type(4)));

#define XS_COLS 66
#define XS_CHP_B 48                            // 16ch*2B + 16B pad; 16-aligned
#define XS_SLOT_B (XS_COLS * XS_CHP_B)         // 3168 B per row-slot
#define H_BYTES 16384                          // H[64 px][128 k] bf16, XOR-swizzled
#define OFF_XS H_BYTES
#define SMEM_BYTES (H_BYTES + 4 * XS_SLOT_B)   // 29056 B

__device__ __forceinline__ unsigned short bfbits(float f) {
    __bf16 b = (__bf16)f;
    return __builtin_bit_cast(unsigned short, b);
}
__device__ __forceinline__ float bf2f(unsigned short u) {
    return __uint_as_float((unsigned int)u << 16);
}

__global__ __launch_bounds__(256, 4) void nca_main(
    const float* __restrict__ x, const float* __restrict__ rm,
    const float* __restrict__ W1, const float* __restrict__ b1,
    const float* __restrict__ W2, const float* __restrict__ b2,
    float* __restrict__ out, unsigned int* __restrict__ am)
{
    __shared__ __align__(16) char smem[SMEM_BYTES];
    char* Hb  = smem;
    char* XSb = smem + OFF_XS;

    const int tid  = threadIdx.x;
    const int lane = tid & 63;
    const int wid  = tid >> 6;      // 0..3
    const int lrow = lane & 15;
    const int kg   = lane >> 4;     // 0..3
    const int kgh  = kg >> 1;       // 0..1
    const int kgl  = kg & 1;

    // block -> (img, row-group of 32, col-strip of 64); 1024 blocks, XCD-chunked
    int raw = blockIdx.x;
    int wg  = (raw & 7) * 128 + (raw >> 3);
    int img = wg >> 5;
    int rem = wg & 31;
    int h0  = (rem >> 2) * 32;
    int w0  = (rem & 3) << 6;

    const size_t imgbase = (size_t)img * 65536;
    const int r = wid;              // n-pair: this wave owns n-tiles 2r, 2r+1

    // ---- Wt fragments (conv folded into W1; 6 nonzero taps, K=96) ----
    // taps tp: 0:(-1,-1) 1:(-1,0) 2:(-1,+1) 3:(0,-1) 4:(0,+1) 5:(+1,0)
    bf16x8 wt[2][3];
    #pragma unroll
    for (int m = 0; m < 2; ++m) {
        int n = (r * 2 + m) * 16 + lrow;
        #pragma unroll
        for (int kk = 0; kk < 3; ++kk) {
            float c0, c1, c2;
            if (kk == 0) {        // tp0 / tp1
                c0 = kgh ? -0.25f : -0.125f; c1 = 0.f; c2 = kgh ? 0.25f : 0.125f;
            } else if (kk == 1) { // tp2 / tp3
                c0 = -0.125f;
                c1 = kgh ? -0.25f  : 0.f;
                c2 = kgh ? -0.125f : 0.125f;
            } else {              // tp4 / tp5
                c0 = kgh ? 0.f : 0.125f; c1 = kgh ? 1.f : 0.25f; c2 = kgh ? 0.f : 0.125f;
            }
            bf16x8 v;
            #pragma unroll
            for (int j = 0; j < 8; ++j) {
                int ch = kgl * 8 + j;
                float wv = c0 * W1[(3 * ch + 0) * 128 + n]
                         + c1 * W1[(3 * ch + 1) * 128 + n]
                         + c2 * W1[(3 * ch + 2) * 128 + n];
                v[j] = (__bf16)wv;
            }
            wt[m][kk] = v;
        }
    }

    // W2 fragments (A-operand of transposed GEMM2: rows = out-channel c = lrow)
    bf16x8 w2f[4];
    #pragma unroll
    for (int kk = 0; kk < 4; ++kk) {
        bf16x8 v;
        #pragma unroll
        for (int j = 0; j < 8; ++j)
            v[j] = (__bf16)W2[(kk * 32 + kg * 8 + j) * 16 + lrow];
        w2f[kk] = v;
    }

    f32x4 b1q[2];
    #pragma unroll
    for (int m = 0; m < 2; ++m)
        b1q[m] = *reinterpret_cast<const f32x4*>(b1 + (r * 2 + m) * 16 + kg * 4);
    const f32x4 b2q = *reinterpret_cast<const f32x4*>(b2 + kg * 4);

    // ---- prologue: stage rows h0-1 .. h0+1 into XS ring (slot = row mod 4) ----
    for (int idx = tid; idx < 3 * 264; idx += 256) {
        int rr  = idx / 264;
        int q   = idx - rr * 264;
        int col = q >> 2, chq = q & 3;
        int gh = h0 - 1 + rr, gw = w0 + col - 1;
        int slot = (gh + 4) & 3;
        float4 v = make_float4(0.f, 0.f, 0.f, 0.f);
        if (gh >= 0 && gh < 256 && gw >= 0 && gw < 256)
            v = *reinterpret_cast<const float4*>(x + (imgbase + (size_t)gh * 256 + gw) * 16 + chq * 4);
        ushort4 qq = { bfbits(v.x), bfbits(v.y), bfbits(v.z), bfbits(v.w) };
        *reinterpret_cast<ushort4*>(XSb + slot * XS_SLOT_B + col * XS_CHP_B + chq * 8) = qq;
    }
    __syncthreads();

    const int pxl2 = wid * 16 + lrow;   // pixel this lane owns in P2 (0..63)

    for (int i = 0; i < 32; ++i) {
        int h = h0 + i;
        int sbm = ((h + 3) & 3) * XS_SLOT_B;   // row h-1
        int sb0 = ((h + 4) & 3) * XS_SLOT_B;   // row h
        int sbp = ((h + 5) & 3) * XS_SLOT_B;   // row h+1

        // ---- issue ALL P2 inputs here: covered by G1's 24 MFMA ----
        const bool do_stage = (i < 31);
        const int gh2 = h + 2;
        float4 sv0 = make_float4(0.f, 0.f, 0.f, 0.f), sv1 = make_float4(0.f, 0.f, 0.f, 0.f);
        if (do_stage) {
            int col0 = tid >> 2, chq0 = tid & 3;
            int gw = w0 + col0 - 1;
            if (gh2 < 256 && gw >= 0 && gw < 256)
                sv0 = *reinterpret_cast<const float4*>(x + (imgbase + (size_t)gh2 * 256 + gw) * 16 + chq0 * 4);
            if (tid < 8) {
                int col1 = 64 + (tid >> 2), gw1 = w0 + col1 - 1;
                if (gh2 < 256 && gw1 >= 0 && gw1 < 256)
                    sv1 = *reinterpret_cast<const float4*>(x + (imgbase + (size_t)gh2 * 256 + gw1) * 16 + (tid & 3) * 4);
            }
        }
        const unsigned int pixi = (unsigned int)(img * 65536 + h * 256 + w0 + pxl2);
        const float rmv = rm[pixi];
        const ushort4 xb = *reinterpret_cast<const ushort4*>(XSb + sb0 + (pxl2 + 1) * XS_CHP_B + kg * 8);

        // ---- P1: GEMM1 (transposed): C1T[n][px]; bias enters via MFMA C-in ----
        __builtin_amdgcn_s_setprio(1);
        #pragma unroll
        for (int t = 0; t < 4; ++t) {
            int pxl = t * 16 + lrow;                    // 0..63
            int colbase = (pxl + 1) * XS_CHP_B + kgl * 16;
            const char* a0p = XSb + sbm + colbase + (kgh ? 0 : -XS_CHP_B);
            const char* a1p = kgh ? (XSb + sb0 + colbase - XS_CHP_B) : (XSb + sbm + colbase + XS_CHP_B);
            const char* a2p = kgh ? (XSb + sbp + colbase)            : (XSb + sb0 + colbase + XS_CHP_B);
            bf16x8 bf0 = *reinterpret_cast<const bf16x8*>(a0p);
            bf16x8 bf1 = *reinterpret_cast<const bf16x8*>(a1p);
            bf16x8 bf2 = *reinterpret_cast<const bf16x8*>(a2p);
            f32x4 a0 = __builtin_amdgcn_mfma_f32_16x16x32_bf16(wt[0][0], bf0, b1q[0], 0, 0, 0);
            f32x4 a1 = __builtin_amdgcn_mfma_f32_16x16x32_bf16(wt[1][0], bf0, b1q[1], 0, 0, 0);
            a0 = __builtin_amdgcn_mfma_f32_16x16x32_bf16(wt[0][1], bf1, a0, 0, 0, 0);
            a1 = __builtin_amdgcn_mfma_f32_16x16x32_bf16(wt[1][1], bf1, a1, 0, 0, 0);
            a0 = __builtin_amdgcn_mfma_f32_16x16x32_bf16(wt[0][2], bf2, a0, 0, 0, 0);
            a1 = __builtin_amdgcn_mfma_f32_16x16x32_bf16(wt[1][2], bf2, a1, 0, 0, 0);
            #pragma unroll
            for (int m = 0; m < 2; ++m) {
                f32x4 hv = m ? a1 : a0;
                ushort4 q;
                q.x = bfbits(fmaxf(hv[0], 0.f));
                q.y = bfbits(fmaxf(hv[1], 0.f));
                q.z = bfbits(fmaxf(hv[2], 0.f));
                q.w = bfbits(fmaxf(hv[3], 0.f));
                int n0 = (r * 2 + m) * 16 + kg * 4;
                int chunk = (n0 >> 3) ^ (pxl & 7);
                *reinterpret_cast<ushort4*>(Hb + pxl * 256 + chunk * 16 + ((n0 >> 2) & 1) * 8) = q;
            }
        }
        __builtin_amdgcn_s_setprio(0);
        __syncthreads();

        // ---- P2: GEMM2T (inputs already resident); am-pack epilogue; stage writes ----
        f32x4 acc2 = {0.f, 0.f, 0.f, 0.f};
        __builtin_amdgcn_s_setprio(1);
        #pragma unroll
        for (int kk = 0; kk < 4; ++kk) {
            int chunk = (4 * kk + kg) ^ (pxl2 & 7);
            bf16x8 hb = *reinterpret_cast<const bf16x8*>(Hb + pxl2 * 256 + chunk * 16);
            acc2 = __builtin_amdgcn_mfma_f32_16x16x32_bf16(w2f[kk], hb, acc2, 0, 0, 0);
        }
        __builtin_amdgcn_s_setprio(0);
        {
            size_t pix = (size_t)pixi;
            float upd = (rmv < 0.5f) ? 1.f : 0.f;
            float4 xn;
            xn.x = bf2f(xb.x) + (acc2[0] + b2q[0]) * upd;
            xn.y = bf2f(xb.y) + (acc2[1] + b2q[1]) * upd;
            xn.z = bf2f(xb.z) + (acc2[2] + b2q[2]) * upd;
            xn.w = bf2f(xb.w) + (acc2[3] + b2q[3]) * upd;
            *reinterpret_cast<float4*>(out + pix * 16 + kg * 4) = xn;
            if (kg == 0) {
                // lo16 = alpha_new, hi16 = alpha_old (xb.w = old ch3 bits for kg==0)
                unsigned int av = ((unsigned int)xb.w << 16) | (unsigned int)bfbits(xn.w);
                am[pix] = av;
            }
        }

        if (do_stage) {
            int slot = (gh2 + 4) & 3;
            {
                int col0 = tid >> 2, chq0 = tid & 3;
                ushort4 q = { bfbits(sv0.x), bfbits(sv0.y), bfbits(sv0.z), bfbits(sv0.w) };
                *reinterpret_cast<ushort4*>(XSb + slot * XS_SLOT_B + col0 * XS_CHP_B + chq0 * 8) = q;
            }
            if (tid < 8) {
                int col1 = 64 + (tid >> 2);
                ushort4 q = { bfbits(sv1.x), bfbits(sv1.y), bfbits(sv1.z), bfbits(sv1.w) };
                *reinterpret_cast<ushort4*>(XSb + slot * XS_SLOT_B + col1 * XS_CHP_B + (tid & 3) * 8) = q;
            }
        }
        __syncthreads();
    }
}

// pass 2: 4 px per thread; both 3x3 masks from packed {alpha_new(lo), alpha_old(hi)}
__global__ __launch_bounds__(256) void nca_life(
    const unsigned int* __restrict__ am, float* __restrict__ out)
{
    int g  = blockIdx.x * 256 + threadIdx.x;   // 524288 groups of 4 px
    int q0 = g << 2;
    int w4 = q0 & 255;                         // 0,4,...,252 (aligned in row)
    int hh = (q0 >> 8) & 255;
    int imgb = q0 & ~0xFFFF;                   // image base index

    // load 3 rows x 6 cols (w4-1 .. w4+4), edge-predicated
    unsigned int v[3][6];
    #pragma unroll
    for (int dh = 0; dh < 3; ++dh) {
        int h2 = hh - 1 + dh;
        bool hv = (h2 >= 0) && (h2 <= 255);
        int base = imgb + h2 * 256;
        #pragma unroll
        for (int dw = 0; dw < 6; ++dw) {
            int w2 = w4 - 1 + dw;
            v[dh][dw] = (hv && w2 >= 0 && w2 <= 255) ? am[base + w2] : 0u;
        }
    }

    #pragma unroll
    for (int p = 0; p < 4; ++p) {
        float mn = -1e30f, mo = -1e30f;
        #pragma unroll
        for (int dh = 0; dh < 3; ++dh)
            #pragma unroll
            for (int dw = 0; dw < 3; ++dw) {
                unsigned int u = v[dh][p + dw];
                mn = fmaxf(mn, __uint_as_float(u << 16));           // alpha_new
                mo = fmaxf(mo, __uint_as_float(u & 0xffff0000u));   // alpha_old
            }
        if (!(mo > 0.1f && mn > 0.1f)) {
            float4 z = make_float4(0.f, 0.f, 0.f, 0.f);
            float4* o = (float4*)(out + (size_t)(q0 + p) * 16);
            o[0] = z; o[1] = z; o[2] = z; o[3] = z;
        }
    }
}

extern "C" void kernel_launch(void* const* d_in, const int* in_sizes, int n_in,
                              void* d_out, int out_size, void* d_ws, size_t ws_size,
                              hipStream_t stream) {
    (void)in_sizes; (void)n_in; (void)out_size; (void)ws_size;
    const float* x  = (const float*)d_in[0];
    const float* rm = (const float*)d_in[1];
    const float* W1 = (const float*)d_in[2];
    const float* b1 = (const float*)d_in[3];
    const float* W2 = (const float*)d_in[4];
    const float* b2 = (const float*)d_in[5];
    float* out = (float*)d_out;
    unsigned int* am = (unsigned int*)d_ws;   // 2M x u32 = 8 MB

    nca_main<<<dim3(1024), dim3(256), 0, stream>>>(x, rm, W1, b1, W2, b2, out, am);
    nca_life<<<dim3(2048), dim3(256), 0, stream>>>(am, out);
}